// Round 3
// baseline (287.815 us; speedup 1.0000x reference)
//
#include <hip/hip_runtime.h>
#include <cstdint>
#include <cstddef>

#pragma clang fp contract(off)

#define A_N 76725
#define C_N 80
#define CA_N (A_N * C_N)          // 6,138,000
#define MAXDET 200
#define CAP 4096
#define IMG_F 640.0f
#define THR0 0.975f
#define CNT_STRIDE 32             // ints; 128 B per counter -> one L2 line each
#define FILLB 2480                // fill-role blocks in k_mega

// ---------------------------------------------------------------------------
// IoU predicate — exact op sequence of the reference.
// ---------------------------------------------------------------------------
__device__ __forceinline__ bool iou_gt(float b0, float b1, float b2, float b3, float ab,
                                       float x0, float x1, float x2, float x3, float xa) {
    float ix1 = fmaxf(b0, x0);
    float iy1 = fmaxf(b1, x1);
    float ix2 = fminf(b2, x2);
    float iy2 = fminf(b3, x3);
    float iw = fmaxf(ix2 - ix1, 0.0f);
    float ih = fmaxf(iy2 - iy1, 0.0f);
    float inter = iw * ih;
    float den = ab + xa - inter;
    float iou = inter / den;
    return iou > 0.5f;
}

__device__ __forceinline__ float band_lo(int b) {
    return 0.975f - 0.025f * (float)b;   // b=0 -> 0.975f exactly (matches THR0)
}

// ---------------------------------------------------------------------------
// K1: fused decode + candidate select (global atomic compaction per class).
// ---------------------------------------------------------------------------
__global__ __launch_bounds__(256) void k_prep(const float* __restrict__ cls,
                                              const float* __restrict__ reg,
                                              const float* __restrict__ anc,
                                              float* __restrict__ boxes,
                                              int* __restrict__ gcnt,
                                              unsigned long long* __restrict__ gkeys) {
    int i = blockIdx.x * 256 + threadIdx.x;
    if (i < A_N) {
        float a0 = anc[i * 4 + 0], a1 = anc[i * 4 + 1];
        float a2 = anc[i * 4 + 2], a3 = anc[i * 4 + 3];
        float aw = a2 - a0;
        float ah = a3 - a1;
        float ax = a0 + 0.5f * aw;
        float ay = a1 + 0.5f * ah;
        float r0 = reg[i * 4 + 0], r1 = reg[i * 4 + 1];
        float r2 = reg[i * 4 + 2], r3 = reg[i * 4 + 3];
        float cx = ax + r0 * 0.1f * aw;
        float cy = ay + r1 * 0.1f * ah;
        float w = aw * expf(r2 * 0.2f);
        float h = ah * expf(r3 * 0.2f);
        float x1 = fminf(fmaxf(cx - 0.5f * w, 0.0f), IMG_F);
        float y1 = fminf(fmaxf(cy - 0.5f * h, 0.0f), IMG_F);
        float x2 = fminf(fmaxf(cx + 0.5f * w, 0.0f), IMG_F);
        float y2 = fminf(fmaxf(cy + 0.5f * h, 0.0f), IMG_F);
        boxes[i * 4 + 0] = x1;
        boxes[i * 4 + 1] = y1;
        boxes[i * 4 + 2] = x2;
        boxes[i * 4 + 3] = y2;
    }
    if (i < CA_N) {
        float s = cls[i];
        if (s > THR0) {
            int c = i % C_N;
            unsigned a = (unsigned)(i / C_N);
            int p = atomicAdd(&gcnt[c * CNT_STRIDE], 1);
            if (p < CAP)
                gkeys[(size_t)c * CAP + p] =
                    ((unsigned long long)__float_as_uint(s) << 32) |
                    (unsigned long long)(0xFFFFFFFFu - a);
        }
    }
}

// ---------------------------------------------------------------------------
// K2: heterogeneous mega-kernel.
//   blocks [0, C_N)       : per-class greedy NMS -> kept records to ws
//   blocks [C_N, C_N+FILLB): grid-stride default-fill of all outputs
// The two roles share no data; fill (HBM-bound) overlaps NMS (latency-bound).
// ---------------------------------------------------------------------------
__global__ __launch_bounds__(1024) void k_mega(const float* __restrict__ cls,
                                               const float* __restrict__ boxes,
                                               const int* __restrict__ gcnt,
                                               const unsigned long long* __restrict__ gkeys,
                                               int* __restrict__ kcnt,
                                               int* __restrict__ kidx,
                                               float* __restrict__ kscr,
                                               float* __restrict__ kboxg,
                                               float4* __restrict__ out4) {
    const int tid = threadIdx.x;

    if (blockIdx.x >= C_N) {
        // ---------------- fill role ----------------------------------------
        int fb = blockIdx.x - C_N;
        const int n4 = (7 * CA_N) / 4;
        const int lab_lo = CA_N / 4;
        const int lab_hi = (2 * CA_N) / 4;
        for (int i = fb * 1024 + tid; i < n4; i += FILLB * 1024) {
            float v = (i >= lab_lo && i < lab_hi) ? -1.0f : 0.0f;
            out4[i] = make_float4(v, v, v, v);
        }
        return;
    }

    // ---------------- NMS role ---------------------------------------------
    const int c = blockIdx.x;
    const int wave = tid >> 6, lane = tid & 63;

    __shared__ unsigned long long keys[CAP];     // 32 KB
    __shared__ float kbox[MAXDET][4];
    __shared__ float karea[MAXDET];
    __shared__ int kIdxL[MAXDET];
    __shared__ float kScrL[MAXDET];
    __shared__ float cbx[64][4];
    __shared__ float car[64];
    __shared__ unsigned int mlo[64], mhi[64];
    __shared__ unsigned char supp[64];
    __shared__ int cntL, keptL;

    volatile unsigned long long* vkeys = keys;

    int kept = 0;

    for (int band = 0;; ++band) {
        int cnt;
        bool last = false;
        if (band == 0) {
            cnt = gcnt[c * CNT_STRIDE];
            if (cnt > CAP) cnt = CAP;
            for (int i = tid; i < cnt; i += 1024)
                keys[i] = gkeys[(size_t)c * CAP + i];
            __syncthreads();
        } else {
            float hiB = band_lo(band - 1);
            float lo = band_lo(band);
            last = (lo <= 0.1f);
            float loEff = last ? 0.1f : lo;
            if (tid == 0) cntL = 0;
            __syncthreads();
            for (int a = tid; a < A_N; a += 1024) {
                float s = cls[(size_t)a * C_N + c];
                if (s > loEff && s <= hiB) {
                    int p = atomicAdd(&cntL, 1);
                    if (p < CAP)
                        keys[p] = ((unsigned long long)__float_as_uint(s) << 32) |
                                  (unsigned long long)(0xFFFFFFFFu - (unsigned)a);
                }
            }
            __syncthreads();
            cnt = cntL < CAP ? cntL : CAP;
        }

        // --- pad to pow2 (min 128 for the wave-local segment scheme) -------
        int n2 = 128;
        while (n2 < cnt) n2 <<= 1;
        for (int i = cnt + tid; i < n2; i += 1024) keys[i] = 0ull;
        __syncthreads();

        // --- bitonic sort, wave-local for j<64 -----------------------------
        for (int k = 2; k <= n2; k <<= 1) {
            // global passes (cross-wave distances)
            for (int j = k >> 1; j >= 64; j >>= 1) {
                for (int i = tid; i < n2; i += 1024) {
                    int ixj = i ^ j;
                    if (ixj > i) {
                        unsigned long long u = keys[i], v = keys[ixj];
                        bool up = ((i & k) == 0);
                        if (up ? (u < v) : (u > v)) { keys[i] = v; keys[ixj] = u; }
                    }
                }
                __syncthreads();
            }
            // wave-local passes: each wave owns a contiguous 128-key segment
            int segs = n2 >> 7;
            for (int seg = wave; seg < segs; seg += 16) {
                int base = seg << 7;
                int j0 = (k >> 1) < 32 ? (k >> 1) : 32;
                for (int j = j0; j > 0; j >>= 1) {
                    int i = base + lane;
                    int ixj = i ^ j;
                    if (ixj > i) {
                        unsigned long long u = vkeys[i], v = vkeys[ixj];
                        bool up = ((i & k) == 0);
                        if (up ? (u < v) : (u > v)) { vkeys[i] = v; vkeys[ixj] = u; }
                    }
                    i = base + 64 + lane;
                    ixj = i ^ j;
                    if (ixj > i) {
                        unsigned long long u = vkeys[i], v = vkeys[ixj];
                        bool up = ((i & k) == 0);
                        if (up ? (u < v) : (u > v)) { vkeys[i] = v; vkeys[ixj] = u; }
                    }
                    __builtin_amdgcn_wave_barrier();
                }
            }
            __syncthreads();
        }

        // --- chunk-of-64 greedy resolve ------------------------------------
        for (int cs = 0; cs < cnt && kept < MAXDET; cs += 64) {
            int nc = (cnt - cs < 64) ? (cnt - cs) : 64;
            float rb0 = 0, rb1 = 0, rb2 = 0, rb3 = 0, rar = 0, rsc = 0;
            int rix = 0;
            if (tid < 64) {
                mlo[tid] = 0;
                mhi[tid] = 0;
                supp[tid] = (tid < nc) ? 0 : 1;
                if (tid < nc) {
                    unsigned long long key = keys[cs + tid];
                    rix = (int)(0xFFFFFFFFu - (unsigned)(key & 0xFFFFFFFFull));
                    rsc = __uint_as_float((unsigned)(key >> 32));
                    rb0 = boxes[rix * 4 + 0];
                    rb1 = boxes[rix * 4 + 1];
                    rb2 = boxes[rix * 4 + 2];
                    rb3 = boxes[rix * 4 + 3];
                    rar = (rb2 - rb0) * (rb3 - rb1);
                    cbx[tid][0] = rb0; cbx[tid][1] = rb1;
                    cbx[tid][2] = rb2; cbx[tid][3] = rb3;
                    car[tid] = rar;
                }
            }
            __syncthreads();

            // suppression by already-kept boxes (64 cands x 16 threads each)
            {
                int i = tid >> 4, jl = tid & 15;
                if (i < nc) {
                    float x0 = cbx[i][0], x1 = cbx[i][1];
                    float x2 = cbx[i][2], x3 = cbx[i][3], xa = car[i];
                    bool s = false;
                    for (int j = jl; j < kept; j += 16) {
                        if (iou_gt(kbox[j][0], kbox[j][1], kbox[j][2], kbox[j][3],
                                   karea[j], x0, x1, x2, x3, xa)) { s = true; break; }
                    }
                    if (s) supp[i] = 1;
                }
            }
            // intra-chunk suppression matrix: mask[i] bit j (j>i)
            {
                int i = tid & 63, jb = tid >> 6;
                if (i < nc) {
                    float b0 = cbx[i][0], b1 = cbx[i][1];
                    float b2 = cbx[i][2], b3 = cbx[i][3], ba = car[i];
                    unsigned int l32 = 0, h32 = 0;
                    for (int j = jb; j < nc; j += 16) {
                        if (j > i) {
                            if (iou_gt(b0, b1, b2, b3, ba,
                                       cbx[j][0], cbx[j][1], cbx[j][2], cbx[j][3], car[j])) {
                                if (j < 32) l32 |= 1u << j;
                                else        h32 |= 1u << (j - 32);
                            }
                        }
                    }
                    if (l32) atomicOr(&mlo[i], l32);
                    if (h32) atomicOr(&mhi[i], h32);
                }
            }
            __syncthreads();

            // wave-0 serial resolve (ballot over 64 lanes)
            if (tid < 64) {
                bool alive = (lane < nc) && (supp[lane] == 0);
                unsigned int myLo = mlo[lane], myHi = mhi[lane];
                int kc = kept;
                while (kc < MAXDET) {
                    unsigned long long av = __ballot(alive);
                    if (av == 0ull) break;
                    int i = (int)__builtin_ctzll(av);
                    unsigned int plo = (unsigned)__shfl((int)myLo, i, 64);
                    unsigned int phi = (unsigned)__shfl((int)myHi, i, 64);
                    unsigned long long mi = ((unsigned long long)phi << 32) | plo;
                    if (lane == i) {
                        kbox[kc][0] = rb0; kbox[kc][1] = rb1;
                        kbox[kc][2] = rb2; kbox[kc][3] = rb3;
                        karea[kc] = rar;
                        kIdxL[kc] = rix;
                        kScrL[kc] = rsc;
                        alive = false;
                    }
                    if ((mi >> lane) & 1ull) alive = false;
                    kc++;
                }
                if (lane == 0) keptL = kc;
            }
            __syncthreads();
            kept = keptL;
        }

        if (kept >= MAXDET || last) break;
    }

    // --- write kept records to workspace (scatter kernel applies them) -----
    if (tid == 0) kcnt[c] = kept;
    for (int i = tid; i < kept; i += 1024) {
        kidx[c * MAXDET + i] = kIdxL[i];
        kscr[c * MAXDET + i] = kScrL[i];
        kboxg[(c * MAXDET + i) * 4 + 0] = kbox[i][0];
        kboxg[(c * MAXDET + i) * 4 + 1] = kbox[i][1];
        kboxg[(c * MAXDET + i) * 4 + 2] = kbox[i][2];
        kboxg[(c * MAXDET + i) * 4 + 3] = kbox[i][3];
    }
}

// ---------------------------------------------------------------------------
// K3: scatter kept entries into outputs (defaults already written by k_mega)
// ---------------------------------------------------------------------------
__global__ __launch_bounds__(256) void k_scatter(const int* __restrict__ kcnt,
                                                 const int* __restrict__ kidx,
                                                 const float* __restrict__ kscr,
                                                 const float* __restrict__ kboxg,
                                                 float* __restrict__ out) {
    int c = blockIdx.x, t = threadIdx.x;
    int k = kcnt[c];
    for (int i = t; i < k; i += 256) {
        int a = kidx[c * MAXDET + i];
        size_t base = (size_t)c * A_N + (size_t)a;
        out[base] = kscr[c * MAXDET + i];                // final_scores
        out[(size_t)CA_N + base] = (float)c;             // final_labels
        size_t bo = (size_t)2 * CA_N + base * 4;         // final_boxes
        out[bo + 0] = kboxg[(c * MAXDET + i) * 4 + 0];
        out[bo + 1] = kboxg[(c * MAXDET + i) * 4 + 1];
        out[bo + 2] = kboxg[(c * MAXDET + i) * 4 + 2];
        out[bo + 3] = kboxg[(c * MAXDET + i) * 4 + 3];
        out[(size_t)6 * CA_N + base] = 1.0f;             // keep
    }
}

extern "C" void kernel_launch(void* const* d_in, const int* in_sizes, int n_in,
                              void* d_out, int out_size, void* d_ws, size_t ws_size,
                              hipStream_t stream) {
    const float* cls = (const float*)d_in[0];   // [1, A, C]
    const float* reg = (const float*)d_in[1];   // [1, A, 4]
    const float* anc = (const float*)d_in[2];   // [A, 4]
    float* out = (float*)d_out;

    // workspace layout (~6 MB)
    int* gcnt = (int*)d_ws;                               // C*CNT_STRIDE ints
    float* boxes = (float*)(gcnt + C_N * CNT_STRIDE);     // 4*A floats
    unsigned long long* gkeys =
        (unsigned long long*)(boxes + 4 * A_N);           // C*CAP u64
    int* kcnt = (int*)(gkeys + (size_t)C_N * CAP);        // C ints
    int* kidx = kcnt + C_N;                               // C*MAXDET ints
    float* kscr = (float*)(kidx + C_N * MAXDET);          // C*MAXDET floats
    float* kboxg = kscr + C_N * MAXDET;                   // C*MAXDET*4 floats

    hipMemsetAsync(gcnt, 0, C_N * CNT_STRIDE * sizeof(int), stream);

    k_prep<<<(CA_N + 255) / 256, 256, 0, stream>>>(cls, reg, anc, boxes, gcnt, gkeys);

    k_mega<<<C_N + FILLB, 1024, 0, stream>>>(cls, boxes, gcnt, gkeys,
                                             kcnt, kidx, kscr, kboxg, (float4*)d_out);

    k_scatter<<<C_N, 256, 0, stream>>>(kcnt, kidx, kscr, kboxg, out);
}

// Round 4
// 276.140 us; speedup vs baseline: 1.0423x; 1.0423x over previous
//
#include <hip/hip_runtime.h>
#include <cstdint>
#include <cstddef>

#pragma clang fp contract(off)

#define A_N 76725
#define C_N 80
#define CA_N (A_N * 80)           // 6,138,000
#define MAXDET 200
#define CAP 4096                  // fallback-path capacity (LDS keys array size)
#define NBIN 16
#define BCAP 256                  // per-bin capacity (expected ~120, 12 sigma margin)
#define IMG_F 640.0f
#define THR0 0.975f
#define CNT_STRIDE 32             // ints; 128 B per counter -> own L2 line
#define FILLB 2480                // fill-role blocks in k_mega

typedef unsigned long long u64;

// ---------------------------------------------------------------------------
// IoU predicate — exact op sequence of the reference.
// ---------------------------------------------------------------------------
__device__ __forceinline__ bool iou_gt(float b0, float b1, float b2, float b3, float ab,
                                       float x0, float x1, float x2, float x3, float xa) {
    float ix1 = fmaxf(b0, x0);
    float iy1 = fmaxf(b1, x1);
    float ix2 = fminf(b2, x2);
    float iy2 = fminf(b3, x3);
    float iw = fmaxf(ix2 - ix1, 0.0f);
    float ih = fmaxf(iy2 - iy1, 0.0f);
    float inter = iw * ih;
    float den = ab + xa - inter;
    float iou = inter / den;
    return iou > 0.5f;
}

__device__ __forceinline__ float band_lo(int b) {
    return 0.975f - 0.025f * (float)b;   // b=0 -> 0.975f exactly (matches THR0)
}

// ---------------------------------------------------------------------------
// K1: fused decode + candidate select with 16-way sub-band binning.
// bin(s) is monotone in s, so (bin desc, score desc, idx asc) == global
// greedy order; equal scores always land in the same bin.
// ---------------------------------------------------------------------------
__global__ __launch_bounds__(256) void k_prep(const float* __restrict__ cls,
                                              const float* __restrict__ reg,
                                              const float* __restrict__ anc,
                                              float* __restrict__ boxes,
                                              int* __restrict__ gcnt,
                                              u64* __restrict__ gkeys) {
    int i = blockIdx.x * 256 + threadIdx.x;
    if (i < A_N) {
        float a0 = anc[i * 4 + 0], a1 = anc[i * 4 + 1];
        float a2 = anc[i * 4 + 2], a3 = anc[i * 4 + 3];
        float aw = a2 - a0;
        float ah = a3 - a1;
        float ax = a0 + 0.5f * aw;
        float ay = a1 + 0.5f * ah;
        float r0 = reg[i * 4 + 0], r1 = reg[i * 4 + 1];
        float r2 = reg[i * 4 + 2], r3 = reg[i * 4 + 3];
        float cx = ax + r0 * 0.1f * aw;
        float cy = ay + r1 * 0.1f * ah;
        float w = aw * expf(r2 * 0.2f);
        float h = ah * expf(r3 * 0.2f);
        float x1 = fminf(fmaxf(cx - 0.5f * w, 0.0f), IMG_F);
        float y1 = fminf(fmaxf(cy - 0.5f * h, 0.0f), IMG_F);
        float x2 = fminf(fmaxf(cx + 0.5f * w, 0.0f), IMG_F);
        float y2 = fminf(fmaxf(cy + 0.5f * h, 0.0f), IMG_F);
        boxes[i * 4 + 0] = x1;
        boxes[i * 4 + 1] = y1;
        boxes[i * 4 + 2] = x2;
        boxes[i * 4 + 3] = y2;
    }
    if (i < CA_N) {
        float s = cls[i];
        if (s > THR0) {
            int c = i % C_N;
            unsigned a = (unsigned)(i / C_N);
            int b = (int)((s - THR0) * 640.0f);
            b = b < 0 ? 0 : (b > (NBIN - 1) ? (NBIN - 1) : b);
            int slot = atomicAdd(&gcnt[(c * NBIN + b) * CNT_STRIDE], 1);
            if (slot < BCAP)
                gkeys[((size_t)(c * NBIN + b) << 8) + slot] =
                    ((u64)__float_as_uint(s) << 32) | (u64)(0xFFFFFFFFu - a);
        }
    }
}

// ---------------------------------------------------------------------------
// Chunk-of-64 greedy resolve over a sorted descending run `seg[0..cnt)`.
// Must be called by all 1024 threads under uniform control flow.
// Returns updated kept count.
// ---------------------------------------------------------------------------
__device__ __forceinline__ int resolve_run(const u64* seg, int cnt, int kept,
                                           const float4* __restrict__ boxes4,
                                           float4* kboxS, float* karea,
                                           int* kIdxL, float* kScrL,
                                           float4* cbxS, float* car,
                                           unsigned int* mlo, unsigned int* mhi,
                                           unsigned char* supp, int* keptL,
                                           int tid, int lane) {
    for (int cs = 0; cs < cnt && kept < MAXDET; cs += 64) {
        int nc = (cnt - cs < 64) ? (cnt - cs) : 64;
        float4 rb = make_float4(0.f, 0.f, 0.f, 0.f);
        float rar = 0.f, rsc = 0.f;
        int rix = 0;
        if (tid < 64) {
            mlo[tid] = 0;
            mhi[tid] = 0;
            supp[tid] = (tid < nc) ? 0 : 1;
            if (tid < nc) {
                u64 key = seg[cs + tid];
                rix = (int)(0xFFFFFFFFu - (unsigned)(key & 0xFFFFFFFFull));
                rsc = __uint_as_float((unsigned)(key >> 32));
                rb = boxes4[rix];
                rar = (rb.z - rb.x) * (rb.w - rb.y);
                cbxS[tid] = rb;
                car[tid] = rar;
            }
        }
        __syncthreads();

        // suppression by already-kept boxes (64 cands x 16 threads each)
        {
            int i = tid >> 4, jl = tid & 15;
            if (i < nc) {
                float4 x = cbxS[i];
                float xa = car[i];
                bool s = false;
                for (int j = jl; j < kept; j += 16) {
                    float4 kb = kboxS[j];
                    if (iou_gt(kb.x, kb.y, kb.z, kb.w, karea[j],
                               x.x, x.y, x.z, x.w, xa)) { s = true; break; }
                }
                if (s) supp[i] = 1;
            }
        }
        // intra-chunk suppression matrix: mask[i] bit j (j>i)
        {
            int i = tid & 63, jb = tid >> 6;
            if (i < nc) {
                float4 b = cbxS[i];
                float ba = car[i];
                unsigned int l32 = 0, h32 = 0;
                for (int j = jb; j < nc; j += 16) {
                    if (j > i) {
                        float4 o = cbxS[j];
                        if (iou_gt(b.x, b.y, b.z, b.w, ba,
                                   o.x, o.y, o.z, o.w, car[j])) {
                            if (j < 32) l32 |= 1u << j;
                            else        h32 |= 1u << (j - 32);
                        }
                    }
                }
                if (l32) atomicOr(&mlo[i], l32);
                if (h32) atomicOr(&mhi[i], h32);
            }
        }
        __syncthreads();

        // wave-0 serial resolve (ballot over 64 lanes)
        if (tid < 64) {
            bool alive = (lane < nc) && (supp[lane] == 0);
            unsigned int myLo = mlo[lane], myHi = mhi[lane];
            int kc = kept;
            while (kc < MAXDET) {
                u64 av = __ballot(alive);
                if (av == 0ull) break;
                int i = (int)__builtin_ctzll(av);
                unsigned int plo = (unsigned)__shfl((int)myLo, i, 64);
                unsigned int phi = (unsigned)__shfl((int)myHi, i, 64);
                u64 mi = ((u64)phi << 32) | plo;
                if (lane == i) {
                    kboxS[kc] = rb;
                    karea[kc] = rar;
                    kIdxL[kc] = rix;
                    kScrL[kc] = rsc;
                    alive = false;
                }
                if ((mi >> lane) & 1ull) alive = false;
                kc++;
            }
            if (lane == 0) *keptL = kc;
        }
        __syncthreads();
        kept = *keptL;
    }
    return kept;
}

// ---------------------------------------------------------------------------
// K2: heterogeneous mega-kernel.
//   blocks [0, C_N)        : per-class greedy NMS -> kept records to ws
//   blocks [C_N, C_N+FILLB): grid-stride default-fill of all outputs
// ---------------------------------------------------------------------------
__global__ __launch_bounds__(1024) void k_mega(const float* __restrict__ cls,
                                               const float* __restrict__ boxes,
                                               const int* __restrict__ gcnt,
                                               const u64* __restrict__ gkeys,
                                               int* __restrict__ kcnt,
                                               int* __restrict__ kidx,
                                               float* __restrict__ kscr,
                                               float* __restrict__ kboxg,
                                               float4* __restrict__ out4) {
    const int tid = threadIdx.x;

    if (blockIdx.x >= C_N) {
        // ---------------- fill role ----------------------------------------
        int fb = blockIdx.x - C_N;
        const int n4 = (7 * CA_N) / 4;
        const int lab_lo = CA_N / 4;
        const int lab_hi = (2 * CA_N) / 4;
        for (int i = fb * 1024 + tid; i < n4; i += FILLB * 1024) {
            float v = (i >= lab_lo && i < lab_hi) ? -1.0f : 0.0f;
            out4[i] = make_float4(v, v, v, v);
        }
        return;
    }

    // ---------------- NMS role ---------------------------------------------
    const int c = blockIdx.x;
    const int wave = tid >> 6, lane = tid & 63;
    const float4* boxes4 = (const float4*)boxes;

    __shared__ u64 keys[CAP];            // 32 KB; bins: wave w -> keys + w*256
    __shared__ int bcnt[NBIN];
    __shared__ float4 kboxS[MAXDET];
    __shared__ float karea[MAXDET];
    __shared__ int kIdxL[MAXDET];
    __shared__ float kScrL[MAXDET];
    __shared__ float4 cbxS[64];
    __shared__ float car[64];
    __shared__ unsigned int mlo[64], mhi[64];
    __shared__ unsigned char supp[64];
    __shared__ int cntL, keptL;

    // --- bin counts ---------------------------------------------------------
    if (tid < NBIN) {
        int v = gcnt[(c * NBIN + tid) * CNT_STRIDE];
        bcnt[tid] = v > BCAP ? BCAP : v;
    }
    __syncthreads();

    // --- per-wave bin load + wave-synchronous bitonic sort (descending) -----
    {
        int cw = bcnt[wave];
        volatile u64* seg = keys + (wave << 8);
        const u64* src = gkeys + ((size_t)(c * NBIN + wave) << 8);
        for (int i = lane; i < cw; i += 64) seg[i] = src[i];
        int n2 = 64;
        while (n2 < cw) n2 <<= 1;
        for (int i = cw + lane; i < n2; i += 64) seg[i] = 0ull;
        __builtin_amdgcn_wave_barrier();
        for (int k = 2; k <= n2; k <<= 1) {
            for (int j = k >> 1; j > 0; j >>= 1) {
                for (int i0 = lane; i0 < n2; i0 += 64) {
                    int ixj = i0 ^ j;
                    if (ixj > i0) {
                        u64 u = seg[i0], v = seg[ixj];
                        bool up = ((i0 & k) == 0);
                        if (up ? (u < v) : (u > v)) { seg[i0] = v; seg[ixj] = u; }
                    }
                }
                __builtin_amdgcn_wave_barrier();
            }
        }
    }
    __syncthreads();

    // --- resolve bins in descending-score order ------------------------------
    int kept = 0;
    for (int b = NBIN - 1; b >= 0; --b) {
        kept = resolve_run(keys + (b << 8), bcnt[b], kept, boxes4,
                           kboxS, karea, kIdxL, kScrL, cbxS, car,
                           mlo, mhi, supp, &keptL, tid, lane);
        if (kept >= MAXDET) break;
    }

    // --- fallback bands (rare): scan, block-sort, resolve --------------------
    if (kept < MAXDET) {
        for (int band = 1;; ++band) {
            float hiB = band_lo(band - 1);
            float lo = band_lo(band);
            bool last = (lo <= 0.1f);
            float loEff = last ? 0.1f : lo;
            if (tid == 0) cntL = 0;
            __syncthreads();
            for (int a = tid; a < A_N; a += 1024) {
                float s = cls[(size_t)a * C_N + c];
                if (s > loEff && s <= hiB) {
                    int p = atomicAdd(&cntL, 1);
                    if (p < CAP)
                        keys[p] = ((u64)__float_as_uint(s) << 32) |
                                  (u64)(0xFFFFFFFFu - (unsigned)a);
                }
            }
            __syncthreads();
            int cnt = cntL < CAP ? cntL : CAP;

            int n2 = 64;
            while (n2 < cnt) n2 <<= 1;
            for (int i = cnt + tid; i < n2; i += 1024) keys[i] = 0ull;
            __syncthreads();
            for (int k = 2; k <= n2; k <<= 1) {
                for (int j = k >> 1; j > 0; j >>= 1) {
                    for (int i = tid; i < n2; i += 1024) {
                        int ixj = i ^ j;
                        if (ixj > i) {
                            u64 u = keys[i], v = keys[ixj];
                            bool up = ((i & k) == 0);
                            if (up ? (u < v) : (u > v)) { keys[i] = v; keys[ixj] = u; }
                        }
                    }
                    __syncthreads();
                }
            }

            kept = resolve_run(keys, cnt, kept, boxes4,
                               kboxS, karea, kIdxL, kScrL, cbxS, car,
                               mlo, mhi, supp, &keptL, tid, lane);
            if (kept >= MAXDET || last) break;
        }
    }

    // --- write kept records to workspace ------------------------------------
    if (tid == 0) kcnt[c] = kept;
    for (int i = tid; i < kept; i += 1024) {
        kidx[c * MAXDET + i] = kIdxL[i];
        kscr[c * MAXDET + i] = kScrL[i];
        float4 kb = kboxS[i];
        kboxg[(c * MAXDET + i) * 4 + 0] = kb.x;
        kboxg[(c * MAXDET + i) * 4 + 1] = kb.y;
        kboxg[(c * MAXDET + i) * 4 + 2] = kb.z;
        kboxg[(c * MAXDET + i) * 4 + 3] = kb.w;
    }
}

// ---------------------------------------------------------------------------
// K3: scatter kept entries into outputs (defaults already written by k_mega)
// ---------------------------------------------------------------------------
__global__ __launch_bounds__(256) void k_scatter(const int* __restrict__ kcnt,
                                                 const int* __restrict__ kidx,
                                                 const float* __restrict__ kscr,
                                                 const float* __restrict__ kboxg,
                                                 float* __restrict__ out) {
    int c = blockIdx.x, t = threadIdx.x;
    int k = kcnt[c];
    for (int i = t; i < k; i += 256) {
        int a = kidx[c * MAXDET + i];
        size_t base = (size_t)c * A_N + (size_t)a;
        out[base] = kscr[c * MAXDET + i];                // final_scores
        out[(size_t)CA_N + base] = (float)c;             // final_labels
        size_t bo = (size_t)2 * CA_N + base * 4;         // final_boxes
        out[bo + 0] = kboxg[(c * MAXDET + i) * 4 + 0];
        out[bo + 1] = kboxg[(c * MAXDET + i) * 4 + 1];
        out[bo + 2] = kboxg[(c * MAXDET + i) * 4 + 2];
        out[bo + 3] = kboxg[(c * MAXDET + i) * 4 + 3];
        out[(size_t)6 * CA_N + base] = 1.0f;             // keep
    }
}

extern "C" void kernel_launch(void* const* d_in, const int* in_sizes, int n_in,
                              void* d_out, int out_size, void* d_ws, size_t ws_size,
                              hipStream_t stream) {
    const float* cls = (const float*)d_in[0];   // [1, A, C]
    const float* reg = (const float*)d_in[1];   // [1, A, 4]
    const float* anc = (const float*)d_in[2];   // [A, 4]
    float* out = (float*)d_out;

    // workspace layout (~4.3 MB)
    int* gcnt = (int*)d_ws;                                  // C*NBIN*CNT_STRIDE ints
    float* boxes = (float*)(gcnt + C_N * NBIN * CNT_STRIDE); // 4*A floats
    u64* gkeys = (u64*)(boxes + 4 * A_N);                    // C*NBIN*BCAP u64
    int* kcnt = (int*)(gkeys + (size_t)C_N * NBIN * BCAP);   // C ints
    int* kidx = kcnt + C_N;                                  // C*MAXDET ints
    float* kscr = (float*)(kidx + C_N * MAXDET);             // C*MAXDET floats
    float* kboxg = kscr + C_N * MAXDET;                      // C*MAXDET*4 floats

    hipMemsetAsync(gcnt, 0, C_N * NBIN * CNT_STRIDE * sizeof(int), stream);

    k_prep<<<(CA_N + 255) / 256, 256, 0, stream>>>(cls, reg, anc, boxes, gcnt, gkeys);

    k_mega<<<C_N + FILLB, 1024, 0, stream>>>(cls, boxes, gcnt, gkeys,
                                             kcnt, kidx, kscr, kboxg, (float4*)d_out);

    k_scatter<<<C_N, 256, 0, stream>>>(kcnt, kidx, kscr, kboxg, out);
}